// Round 8
// baseline (671.278 us; speedup 1.0000x reference)
//
#include <hip/hip_runtime.h>
#include <hip/hip_bf16.h>

#define NN 50000
#define NE 800000
#define FD 80
#define NGR 1024
#define NF 9

using bf16 = __hip_bfloat16;
typedef __attribute__((ext_vector_type(8))) short bf16x8;
typedef __attribute__((ext_vector_type(4))) float f32x4;

static __device__ __forceinline__ float b2f(bf16 v){ return __bfloat162float(v); }
static __device__ __forceinline__ bf16 f2b(float v){ return __float2bfloat16(v); }
static __device__ __forceinline__ float rdw(const void* p, int i, int fl){
  return fl ? ((const float*)p)[i] : b2f(((const bf16*)p)[i]);
}
static __device__ __forceinline__ unsigned pk(float a, float b){
  bf16 x = f2b(a), y = f2b(b);
  return (unsigned)*(unsigned short*)&x | ((unsigned)*(unsigned short*)&y << 16);
}

// ------------------------------------------------------------------ utility
__global__ void k_zero(int* __restrict__ p, int n){
  int t = blockIdx.x*256 + threadIdx.x;
  if (t < n) p[t] = 0;
}

__global__ void k_probe(const void* __restrict__ emb, int* __restrict__ flag){
  int t = blockIdx.x*256 + threadIdx.x;
  float v = b2f(((const bf16*)emb)[t]);
  if (!(fabsf(v) < 1e4f)) atomicOr(flag, 1);
}

// ------------------------------------------------------------------ fused weight prep
__global__ __launch_bounds__(256) void k_prep_all(
    const void* __restrict__ preW, const void* __restrict__ preb,
    const void* __restrict__ postW, const void* __restrict__ postb,
    const void* __restrict__ linW, const void* __restrict__ linb,
    const void* __restrict__ bng, const void* __restrict__ bnb,
    const void* __restrict__ bnm, const void* __restrict__ bnv,
    const int* __restrict__ flag,
    bf16* __restrict__ pwb, bf16* __restrict__ Btl, bf16* __restrict__ Bt1,
    float* __restrict__ bias1, float* __restrict__ bias2)
{
  int fl = flag[0];
  int b = blockIdx.x;
  if (b < 1300){
    int t = b*256 + threadIdx.x;
    pwb[t] = f2b(rdw(postW, t, fl));
  } else if (b < 1420){
    int t = (b - 1300)*256 + threadIdx.x;
    int j = t % 96, c = (t/96) % 80, i = t/(96*80);
    float v = 0.f;
    if (j < 80){
      float gs = rdw(bng, i*80 + c, fl) * rsqrtf(rdw(bnv, i*80 + c, fl) + 1e-5f);
      v = rdw(linW, i*6400 + j*80 + c, fl) * gs;
    }
    Btl[t] = f2b(v);
  } else if (b < 1660){
    int t = (b - 1420)*256 + threadIdx.x;
    int k = t % 96, c = (t/96) % 160, i = t/(96*160);
    float v = 0.f;
    if (k < 80)
      v = (c < 80) ? rdw(preW, (i*160 + k)*80 + c, fl)
                   : rdw(preW, (i*160 + 80 + k)*80 + (c - 80), fl);
    Bt1[t] = f2b(v);
    if (k == 0) bias1[i*160 + c] = (c < 80) ? rdw(preb, i*80 + c, fl) : 0.f;
  } else {
    int t = (b - 1660)*256 + threadIdx.x;
    if (t >= 4*80) return;
    int i = t / 80, f = t - i*80;
    float s = 0.f;
    for (int j = 0; j < 80; j++)
      s += rdw(postb, i*80 + j, fl) * rdw(linW, (i*80 + j)*80 + f, fl);
    s += rdw(linb, t, fl);
    float gs = rdw(bng, t, fl) * rsqrtf(rdw(bnv, t, fl) + 1e-5f);
    bias2[t] = (s - rdw(bnm, t, fl)) * gs + rdw(bnb, t, fl);
  }
}

// Bt2[i][c][k] (c<240 cols, 416-k) from Wf (f32 [i][1040][80]).
__global__ void k_prep_Bt2(const float* __restrict__ Wf, bf16* __restrict__ Bt2){
  int t = blockIdx.x*256 + threadIdx.x;
  if (t >= 4*240*416) return;
  int k = t % 416;
  int c = (t/416) % 240;
  int i = t/(416*240);
  float v = 0.f;
  if (k < 400){
    int blk = c/80, f = c - blk*80;
    if (blk == 0) v = Wf[(i*1040 + k)*80 + f];
    else if (k >= 80){
      int row = (blk == 1 ? 400 : 720) + (k - 80);
      v = Wf[(i*1040 + row)*80 + f];
    }
  }
  Bt2[t] = f2b(v);
}

// ------------------------------------------------------------------ graph prep
__global__ void k_atom(const int* __restrict__ x, const void* __restrict__ emb,
                       const int* __restrict__ flag, float* __restrict__ h){
  int fl = flag[0];
  int gid = blockIdx.x*256 + threadIdx.x;
  if (gid >= NN*FD) return;
  int n = gid / FD, f = gid - n*FD;
  float s = 0.f;
  #pragma unroll
  for (int c = 0; c < NF; c++){
    int row = x[n*NF + c];
    s += rdw(emb, (c*119 + row)*FD + f, fl);
  }
  h[gid] = s;
}

__global__ void k_deg(const int* __restrict__ ei, int* __restrict__ deg){
  int e = blockIdx.x*256 + threadIdx.x;
  if (e < NE) atomicAdd(&deg[ei[NE + e]], 1);
}

__global__ __launch_bounds__(256) void k_scan1(const int* __restrict__ deg, int* __restrict__ bsum){
  __shared__ int buf[256];
  int idx = blockIdx.x*256 + threadIdx.x;
  buf[threadIdx.x] = (idx < NN) ? deg[idx] : 0;
  __syncthreads();
  for (int off = 128; off > 0; off >>= 1){
    if (threadIdx.x < off) buf[threadIdx.x] += buf[threadIdx.x + off];
    __syncthreads();
  }
  if (threadIdx.x == 0) bsum[blockIdx.x] = buf[0];
}

__global__ __launch_bounds__(256) void k_scan2(int* __restrict__ bsum, int* __restrict__ rowptr){
  __shared__ int buf[256];
  int t = threadIdx.x;
  int v = (t < 196) ? bsum[t] : 0;
  buf[t] = v;
  __syncthreads();
  for (int off = 1; off < 256; off <<= 1){
    int xv = (t >= off) ? buf[t - off] : 0;
    __syncthreads();
    buf[t] += xv;
    __syncthreads();
  }
  if (t < 196) bsum[t] = buf[t] - v;
  if (t == 255) rowptr[NN] = buf[255];
}

__global__ __launch_bounds__(256) void k_scan3(const int* __restrict__ deg,
                        const int* __restrict__ bsum, const void* __restrict__ avgp,
                        const int* __restrict__ flag, int* __restrict__ rowptr,
                        float* __restrict__ scf, float* __restrict__ invf){
  __shared__ int buf[256];
  int t = threadIdx.x;
  int idx = blockIdx.x*256 + t;
  int v = (idx < NN) ? deg[idx] : 0;
  buf[t] = v;
  __syncthreads();
  for (int off = 1; off < 256; off <<= 1){
    int xv = (t >= off) ? buf[t - off] : 0;
    __syncthreads();
    buf[t] += xv;
    __syncthreads();
  }
  if (idx < NN){
    rowptr[idx] = bsum[blockIdx.x] + buf[t] - v;
    float degc = (float)(v > 0 ? v : 1);
    float logd = logf(degc + 1.f);
    float avg = rdw(avgp, 0, flag[0]);
    scf[idx] = logd / avg;
    invf[idx] = avg / logd;
  }
}

__global__ void k_scatter(const int* __restrict__ ei, const int* __restrict__ rowptr,
                          int* __restrict__ cursor, int* __restrict__ colidx){
  int e = blockIdx.x*256 + threadIdx.x;
  if (e >= NE) return;
  int d = ei[NE + e];
  int pos = rowptr[d] + atomicAdd(&cursor[d], 1);
  colidx[pos] = ei[e];
}

// ------------------------------------------------------------------ MFMA GEMM
// 64-row x 256-col block tile, 4 waves; wave w = all 64 rows x cols [w*64, w*64+64).
// Per wave per k-iter: af[4], bfv[4], 16 MFMA (acc 4x4 f32x4).
// OUTMODE: 1 = f32 out (stride Cstride); 2 = split bf16 (Ua|Ub);
// 3 = fused PNA epilogue: h += relu(P + sc*Q + inv*R + bias) via LDS staging.
// A rows: k<KA from A1 (f32 if AF32, stride s1); KA<=k<KA+KB from A2 (bf16, s2); else 0.
template<int AF32, int OUTMODE>
__global__ __launch_bounds__(256) void k_mgemm(
    const void* __restrict__ A1p, int s1, int KA,
    const bf16* __restrict__ A2, int s2, int KB,
    const bf16* __restrict__ Btp, int Bts, int Ncols,
    const float* __restrict__ bias,
    void* __restrict__ Cbase, void* __restrict__ Cp2, int Cstride, int M, int K,
    const float* __restrict__ scf, const float* __restrict__ invf,
    int lA1b, int lBtb, int lCb)
{
  const void* A1 = (const char*)A1p + (size_t)blockIdx.z*lA1b;
  const bf16* Bt = (const bf16*)((const char*)Btp + (size_t)blockIdx.z*lBtb);
  void* Cp = (char*)Cbase + (size_t)blockIdx.z*lCb;

  __shared__ char smem[(OUTMODE == 3) ? 31744 : 25600];
  short* As = (short*)smem;            // 64 x 40 shorts = 5120 B
  short* Bs = (short*)(smem + 5120);   // 256 x 40 shorts = 20480 B
  bf16*  eL = (bf16*)smem;             // epilogue staging 64 x 248 bf16 (reuse)

  const int tid = threadIdx.x;
  const int row0 = blockIdx.x * 64;
  const int wave = tid >> 6, lane = tid & 63;
  const int wc = wave * 64;
  const int m16 = lane & 15, q = lane >> 4;

  // A loader: all 256 threads, row tid>>2 (0..63), chunk (tid&3)*8
  const int ra = tid >> 2, ka = (tid & 3) * 8;
  const int cb = tid >> 2, kb = (tid & 3) * 8;

  f32x4 acc[4][4] = {};
  uint4 pa;
  uint4 pb[4];

  const int nk = (K + 31) >> 5;

  // ---- load k-tile 0 into regs
  {
    int kg = ka;
    pa.x = pa.y = pa.z = pa.w = 0u;
    int grow = row0 + ra;
    if (grow < M){
      if (kg < KA){
        if (AF32){
          const float* ap = (const float*)A1 + grow*s1 + kg;
          float4 f0 = *(const float4*)ap;
          float4 f1 = *(const float4*)(ap + 4);
          pa.x = pk(f0.x, f0.y); pa.y = pk(f0.z, f0.w);
          pa.z = pk(f1.x, f1.y); pa.w = pk(f1.z, f1.w);
        } else {
          pa = *(const uint4*)((const bf16*)A1 + grow*s1 + kg);
        }
      } else if (kg - KA < KB){
        pa = *(const uint4*)(A2 + grow*s2 + (kg - KA));
      }
    }
    #pragma unroll
    for (int j = 0; j < 4; j++){
      int col = cb + j*64;
      pb[j].x = pb[j].y = pb[j].z = pb[j].w = 0u;
      if (col < Ncols) pb[j] = *(const uint4*)(Bt + col*Bts + kb);
    }
  }

  for (int ks = 0; ks < nk; ks++){
    // ---- regs -> LDS
    *(uint4*)(&As[ra*40 + ka]) = pa;
    #pragma unroll
    for (int j = 0; j < 4; j++)
      *(uint4*)(&Bs[(cb + j*64)*40 + kb]) = pb[j];
    __syncthreads();

    // ---- prefetch next k-tile (overlaps ds_read + MFMA below)
    if (ks + 1 < nk){
      int k0 = (ks + 1) << 5;
      int kg = k0 + ka;
      pa.x = pa.y = pa.z = pa.w = 0u;
      int grow = row0 + ra;
      if (grow < M){
        if (kg < KA){
          if (AF32){
            const float* ap = (const float*)A1 + grow*s1 + kg;
            float4 f0 = *(const float4*)ap;
            float4 f1 = *(const float4*)(ap + 4);
            pa.x = pk(f0.x, f0.y); pa.y = pk(f0.z, f0.w);
            pa.z = pk(f1.x, f1.y); pa.w = pk(f1.z, f1.w);
          } else {
            pa = *(const uint4*)((const bf16*)A1 + grow*s1 + kg);
          }
        } else if (kg - KA < KB){
          pa = *(const uint4*)(A2 + grow*s2 + (kg - KA));
        }
      }
      int kgb = k0 + kb;
      #pragma unroll
      for (int j = 0; j < 4; j++){
        int col = cb + j*64;
        pb[j].x = pb[j].y = pb[j].z = pb[j].w = 0u;
        if (col < Ncols) pb[j] = *(const uint4*)(Bt + col*Bts + kgb);
      }
    }

    // ---- fragments + MFMA (16 per wave per iter)
    bf16x8 af[4], bfv[4];
    #pragma unroll
    for (int t = 0; t < 4; t++){
      af[t]  = *(const bf16x8*)(&As[(t*16 + m16)*40 + q*8]);
      bfv[t] = *(const bf16x8*)(&Bs[(wc + t*16 + m16)*40 + q*8]);
    }
    #pragma unroll
    for (int rt = 0; rt < 4; rt++)
      #pragma unroll
      for (int ct = 0; ct < 4; ct++)
        acc[rt][ct] = __builtin_amdgcn_mfma_f32_16x16x32_bf16(af[rt], bfv[ct], acc[rt][ct], 0, 0, 0);
    __syncthreads();
  }

  // ---- epilogue
  if (OUTMODE == 3){
    // stage P|Q|R (bf16) in LDS, then combine into h
    #pragma unroll
    for (int rt = 0; rt < 4; rt++){
      #pragma unroll
      for (int ct = 0; ct < 4; ct++){
        int col = wc + ct*16 + m16;
        if (col >= 240) continue;
        #pragma unroll
        for (int rr = 0; rr < 4; rr++){
          int r = rt*16 + q*4 + rr;
          eL[r*248 + col] = f2b(acc[rt][ct][rr]);
        }
      }
    }
    __syncthreads();
    float* hp = (float*)Cp;
    #pragma unroll
    for (int i = 0; i < 20; i++){
      int idx = tid + i*256;
      int r = idx / 80, c = idx - r*80;
      int row = row0 + r;
      if (row < M){
        float P = b2f(eL[r*248 + c]);
        float Q = b2f(eL[r*248 + 80 + c]);
        float R = b2f(eL[r*248 + 160 + c]);
        float o = P + scf[row]*Q + invf[row]*R + bias[c];
        hp[row*80 + c] += fmaxf(o, 0.f);
      }
    }
  } else {
    #pragma unroll
    for (int rt = 0; rt < 4; rt++){
      #pragma unroll
      for (int rr = 0; rr < 4; rr++){
        int row = row0 + rt*16 + q*4 + rr;
        if (row >= M) continue;
        #pragma unroll
        for (int ct = 0; ct < 4; ct++){
          int col = wc + ct*16 + m16;
          if (col >= Ncols) continue;
          float v = acc[rt][ct][rr] + (bias ? bias[col] : 0.f);
          if (OUTMODE == 1) ((float*)Cp)[row*Cstride + col] = v;
          else {
            if (col < 80) ((bf16*)Cp )[row*80 + col]      = f2b(v);
            else          ((bf16*)Cp2)[row*80 + col - 80] = f2b(v);
          }
        }
      }
    }
  }
}

// ------------------------------------------------------------------ aggregation
// 3 nodes/wave: lane/20 = node slot, (lane%20)*4 = feature offset (uint2 = 4 bf16)
__global__ __launch_bounds__(256) void k_agg(const bf16* __restrict__ Ua,
                      const bf16* __restrict__ Ub,
                      const int* __restrict__ rowptr,
                      const int* __restrict__ colidx, bf16* __restrict__ agg)
{
  int lane = threadIdx.x & 63;
  int slot = lane / 20;
  int n = blockIdx.x*12 + (threadIdx.x >> 6)*3 + slot;
  if (slot >= 3 || n >= NN) return;
  int fo = (lane - slot*20) * 4;
  int rs = rowptr[n], re = rowptr[n+1];
  int deg = re - rs;

  float a[4];
  {
    uint2 ua = *(const uint2*)(Ua + n*80 + fo);
    a[0] = __uint_as_float(ua.x << 16);
    a[1] = __uint_as_float(ua.x & 0xffff0000u);
    a[2] = __uint_as_float(ua.y << 16);
    a[3] = __uint_as_float(ua.y & 0xffff0000u);
  }
  float sb[4] = {0.f,0.f,0.f,0.f}, sq[4] = {0.f,0.f,0.f,0.f};
  float mn[4] = {1e30f,1e30f,1e30f,1e30f}, mx[4] = {-1e30f,-1e30f,-1e30f,-1e30f};

#define ACC2(w, o) { \
    float b0 = __uint_as_float((w) << 16); \
    float b1 = __uint_as_float((w) & 0xffff0000u); \
    sb[o] += b0; sq[o] += b0*b0; mn[o] = fminf(mn[o],b0); mx[o] = fmaxf(mx[o],b0); \
    sb[o+1] += b1; sq[o+1] += b1*b1; mn[o+1] = fminf(mn[o+1],b1); mx[o+1] = fmaxf(mx[o+1],b1); }

  for (int e = rs; e < re; e += 8){
    int cnt = re - e; if (cnt > 8) cnt = 8;
    int s[8];
    #pragma unroll
    for (int j = 0; j < 8; j++) s[j] = (j < cnt) ? colidx[e + j] : s[0];
    uint2 u[8];
    #pragma unroll
    for (int j = 0; j < 8; j++) u[j] = *(const uint2*)(Ub + s[j]*80 + fo);
    #pragma unroll
    for (int j = 0; j < 8; j++){
      if (j < cnt){ ACC2(u[j].x, 0); ACC2(u[j].y, 2); }
    }
  }
#undef ACC2

  float degc = (float)(deg > 0 ? deg : 1);
  float inv = 1.f/degc;
  float dm = (float)deg;
  float mean0, mean1, v0, v1, sd0, sd1, lo0, lo1, hi0, hi1;

  mean0 = (dm*a[0] + sb[0])*inv; mean1 = (dm*a[1] + sb[1])*inv;
  v0 = (dm*a[0]*a[0] + 2.f*a[0]*sb[0] + sq[0])*inv - mean0*mean0;
  v1 = (dm*a[1]*a[1] + 2.f*a[1]*sb[1] + sq[1])*inv - mean1*mean1;
  sd0 = sqrtf(fmaxf(v0,0.f)+1e-5f); sd1 = sqrtf(fmaxf(v1,0.f)+1e-5f);
  lo0 = deg>0 ? a[0]+mn[0] : 0.f; lo1 = deg>0 ? a[1]+mn[1] : 0.f;
  hi0 = deg>0 ? a[0]+mx[0] : 0.f; hi1 = deg>0 ? a[1]+mx[1] : 0.f;
  unsigned o0 = pk(mean0, mean1);
  unsigned l0 = pk(lo0, lo1), h0 = pk(hi0, hi1), t0 = pk(sd0, sd1);

  mean0 = (dm*a[2] + sb[2])*inv; mean1 = (dm*a[3] + sb[3])*inv;
  v0 = (dm*a[2]*a[2] + 2.f*a[2]*sb[2] + sq[2])*inv - mean0*mean0;
  v1 = (dm*a[3]*a[3] + 2.f*a[3]*sb[3] + sq[3])*inv - mean1*mean1;
  sd0 = sqrtf(fmaxf(v0,0.f)+1e-5f); sd1 = sqrtf(fmaxf(v1,0.f)+1e-5f);
  lo0 = deg>0 ? a[2]+mn[2] : 0.f; lo1 = deg>0 ? a[3]+mn[3] : 0.f;
  hi0 = deg>0 ? a[2]+mx[2] : 0.f; hi1 = deg>0 ? a[3]+mx[3] : 0.f;
  unsigned o1 = pk(mean0, mean1);
  unsigned l1 = pk(lo0, lo1), h1 = pk(hi0, hi1), t1 = pk(sd0, sd1);

  bf16* ag = agg + n*320 + fo;
  *(uint2*)(ag)       = make_uint2(o0, o1);
  *(uint2*)(ag + 80)  = make_uint2(l0, l1);
  *(uint2*)(ag + 160) = make_uint2(h0, h1);
  *(uint2*)(ag + 240) = make_uint2(t0, t1);
}

// ------------------------------------------------------------------ fused mean-pool + head
__global__ __launch_bounds__(128) void k_poolmlp(const float* __restrict__ h,
                        const int* __restrict__ batch,
                        const void* __restrict__ mlpW, const void* __restrict__ mlpb,
                        const int* __restrict__ flag, void* __restrict__ outp){
  __shared__ float sred[128];
  __shared__ int sb[2];
  int g = blockIdx.x;
  int t = threadIdx.x;
  if (t < 2){
    int target = g + t;
    int lo = 0, hi = NN;
    while (lo < hi){ int mid = (lo + hi) >> 1; if (batch[mid] < target) lo = mid + 1; else hi = mid; }
    sb[t] = lo;
  }
  __syncthreads();
  int lo = sb[0], hi = sb[1];
  float s = 0.f;
  if (t < 80)
    for (int n = lo; n < hi; n++) s += h[n*80 + t];
  int fl = flag[0];
  float wv = (t < 80) ? rdw(mlpW, t, fl) : 0.f;
  sred[t] = s * wv;
  __syncthreads();
  for (int off = 64; off > 0; off >>= 1){
    if (t < off) sred[t] += sred[t + off];
    __syncthreads();
  }
  if (t == 0){
    float cnt = (float)(hi - lo); if (cnt < 1.f) cnt = 1.f;
    float r = sred[0]/cnt + rdw(mlpb, 0, fl);
    if (fl) ((float*)outp)[g] = r;
    else    ((bf16*)outp)[g] = f2b(r);
  }
}

// ------------------------------------------------------------------ launch
extern "C" void kernel_launch(void* const* d_in, const int* in_sizes, int n_in,
                              void* d_out, int out_size, void* d_ws, size_t ws_size,
                              hipStream_t stream)
{
  const int*  x     = (const int*) d_in[0];
  const int*  ei    = (const int*) d_in[1];
  const int*  batch = (const int*) d_in[2];
  const void* avgp  = d_in[3];
  const void* aemb  = d_in[4];
  const void* preW  = d_in[5];
  const void* preb  = d_in[6];
  const void* postW = d_in[7];
  const void* postb = d_in[8];
  const void* linW  = d_in[9];
  const void* linb  = d_in[10];
  const void* bng   = d_in[11];
  const void* bnb   = d_in[12];
  const void* bnm   = d_in[13];
  const void* bnv   = d_in[14];
  const void* mlpW  = d_in[15];
  const void* mlpb  = d_in[16];

  char* w = (char*)d_ws;
  int*   deg    = (int*)  (w + 0);            //   200,000  (zeroed)
  int*   cursor = (int*)  (w + 200000);       //   200,000  (zeroed)
  int*   flag   = (int*)  (w + 400000);       //       256  (zero region = 400,256 B)
  int*   bsum   = (int*)  (w + 400256);       //     1,024
  int*   rowptr = (int*)  (w + 401280);       //   200,064
  int*   colidx = (int*)  (w + 601344);       // 3,200,000
  float* scf    = (float*)(w + 3801344);      //   200,000
  float* invf   = (float*)(w + 4001344);      //   200,000
  float* bias1  = (float*)(w + 4201344);      //     2,560
  float* bias2  = (float*)(w + 4203904);      //     1,280
  bf16*  Btl    = (bf16*) (w + 4205184);      //    61,440
  bf16*  Bt1    = (bf16*) (w + 4266624);      //   122,880
  bf16*  Bt2    = (bf16*) (w + 4389504);      //   798,720
  float* h      = (float*)(w + 5188224);      // 16,000,000  f32 [N,80]
  bf16*  Ua     = (bf16*) (w + 21188224);     //  8,000,000  bf16 [N,80]
  bf16*  Ub     = (bf16*) (w + 29188224);     //  8,000,000  bf16 [N,80]
  bf16*  agg    = (bf16*) (w + 45188224);     // 32,000,000  bf16 [N,320]
  bf16*  pwb    = (bf16*) (w + 45188224);     //   665,600   (overlay in agg, pre-loop use)
  float* Wf     = (float*)(w + 45853824);     // 1,331,200   (overlay in agg)
  // total 77,188,224 B

  k_zero <<<(100064 + 255)/256, 256, 0, stream>>>((int*)w, 100064);
  k_probe<<<16, 256, 0, stream>>>(aemb, flag);

  k_prep_all<<<1662, 256, 0, stream>>>(preW, preb, postW, postb, linW, linb,
                                       bng, bnb, bnm, bnv, flag,
                                       pwb, Btl, Bt1, bias1, bias2);

  // Wf[i] = postW[i](bf16) @ Btl[i]^T   (f32 out)
  k_mgemm<0,1><<<dim3(17,1,4), 256, 0, stream>>>(
      pwb, 80, 80, nullptr, 0, 0,
      Btl, 96, 80, nullptr, Wf, nullptr, 80, 1040, 96,
      nullptr, nullptr, 166400, 15360, 332800);
  k_prep_Bt2<<<(4*240*416 + 255)/256, 256, 0, stream>>>(Wf, Bt2);

  k_atom <<<(NN*FD + 255)/256, 256, 0, stream>>>(x, aemb, flag, h);
  k_deg  <<<(NE + 255)/256, 256, 0, stream>>>(ei, deg);
  k_scan1<<<196, 256, 0, stream>>>(deg, bsum);
  k_scan2<<<1, 256, 0, stream>>>(bsum, rowptr);
  k_scan3<<<196, 256, 0, stream>>>(deg, bsum, avgp, flag, rowptr, scf, invf);
  k_scatter<<<(NE + 255)/256, 256, 0, stream>>>(ei, rowptr, cursor, colidx);

  const int gx = (NN + 63)/64;   // 782
  for (int i = 0; i < 4; i++){
    // GEMM1: [h] @ Bt1 -> Ua|Ub  (K=96, Ncols=160)
    k_mgemm<1,2><<<dim3(gx,1,1), 256, 0, stream>>>(
        h, 80, 80, nullptr, 0, 0,
        Bt1 + i*15360, 96, 160, bias1 + i*160, Ua, Ub, 0, NN, 96,
        nullptr, nullptr, 0, 0, 0);
    k_agg<<<(NN + 11)/12, 256, 0, stream>>>(Ua, Ub, rowptr, colidx, agg);
    // GEMM2 fused: h += relu(P + sc*Q + inv*R + bias2)  (K=416, Ncols=240)
    k_mgemm<1,3><<<dim3(gx,1,1), 256, 0, stream>>>(
        h, 80, 80, agg, 320, 320,
        Bt2 + i*99840, 416, 240, bias2 + i*80, h, nullptr, 80, NN, 416,
        scf, invf, 0, 0, 0);
  }

  k_poolmlp<<<NGR, 128, 0, stream>>>(h, batch, mlpW, mlpb, flag, d_out);
}